// Round 5
// baseline (324.170 us; speedup 1.0000x reference)
//
#include <hip/hip_runtime.h>
#include <cstdint>

typedef _Float16 f16x8 __attribute__((ext_vector_type(8)));
typedef _Float16 f16x4 __attribute__((ext_vector_type(4)));
typedef float    f32x4 __attribute__((ext_vector_type(4)));

#define AS1 __attribute__((address_space(1)))
#define AS3 __attribute__((address_space(3)))

__device__ __forceinline__ void load16_lds(const void* g, void* l) {
  __builtin_amdgcn_global_load_lds((AS1 void*)g, (AS3 void*)l, 16, 0, 0);
}

// Shared K-loop body macro: stages 128x32 A/B tiles, runs 4x4 MFMA.
// SWAPPED variant: acc[i][j][r] = C[m = wm+16i+l16][n = wn+16j+quad*4+r]
// NORMAL  variant: acc[i][j][r] = C[m = wm+16i+quad*4+r][n = wn+16j+l16]
#define GEMM_PROLOGUE(Ab, lda, Bb, ldb)                                   \
  __shared__ _Float16 lA[128 * 32];                                       \
  __shared__ _Float16 lB[128 * 32];                                       \
  int tid = threadIdx.x;                                                  \
  int r0 = tid >> 2;                                                      \
  int c0 = (tid & 3) * 8;                                                 \
  const _Float16* ga0 = Ab + (long long)r0 * lda + c0;                    \
  const _Float16* ga1 = Ab + (long long)(r0 + 64) * lda + c0;             \
  const _Float16* gb0 = Bb + (long long)r0 * ldb + c0;                    \
  const _Float16* gb1 = Bb + (long long)(r0 + 64) * ldb + c0;             \
  _Float16* la0 = lA + tid * 8;                                           \
  _Float16* la1 = lA + 2048 + tid * 8;                                    \
  _Float16* lb0 = lB + tid * 8;                                           \
  _Float16* lb1 = lB + 2048 + tid * 8;                                    \
  f32x4 acc[4][4] = {};                                                   \
  int lane = tid & 63;                                                    \
  int wv = tid >> 6;                                                      \
  int wm = (wv & 1) * 64, wn = (wv >> 1) * 64;                            \
  int l16 = lane & 15, quad = lane >> 4;                                  \
  const _Float16* raBase = lA + (wm + l16) * 32 + quad * 8;               \
  const _Float16* rbBase = lB + (wn + l16) * 32 + quad * 8;

#define GEMM_KLOOP(lda, ldb, KLEN, SWAP)                                  \
  for (int kb = 0; kb < (KLEN); kb += 32) {                               \
    __syncthreads();                                                      \
    load16_lds(ga0, la0);                                                 \
    load16_lds(ga1, la1);                                                 \
    load16_lds(gb0, lb0);                                                 \
    load16_lds(gb1, lb1);                                                 \
    ga0 += 32; ga1 += 32; gb0 += 32; gb1 += 32;                           \
    __syncthreads();                                                      \
    f16x8 af[4], bfr[4];                                                  \
    _Pragma("unroll")                                                     \
    for (int i = 0; i < 4; i++) af[i] = *(const f16x8*)(raBase + i * 512);\
    _Pragma("unroll")                                                     \
    for (int j = 0; j < 4; j++) bfr[j] = *(const f16x8*)(rbBase + j * 512);\
    _Pragma("unroll")                                                     \
    for (int i = 0; i < 4; i++)                                           \
      _Pragma("unroll")                                                   \
      for (int j = 0; j < 4; j++)                                         \
        acc[i][j] = (SWAP)                                                \
          ? __builtin_amdgcn_mfma_f32_16x16x32_f16(bfr[j], af[i], acc[i][j], 0, 0, 0) \
          : __builtin_amdgcn_mfma_f32_16x16x32_f16(af[i], bfr[j], acc[i][j], 0, 0, 0);\
  }

// ---------------- fused fp32 -> fp16 convert for all 5 inputs ----------------
__global__ __launch_bounds__(256) void cvt_all(
    const float* __restrict__ x, const float* __restrict__ wq,
    const float* __restrict__ wk, const float* __restrict__ wv,
    const float* __restrict__ wo,
    _Float16* __restrict__ xh, _Float16* __restrict__ wcat,
    _Float16* __restrict__ woh) {
  long long g = (long long)blockIdx.x * 256 + threadIdx.x;
  const float* in; _Float16* out; long long idx;
  if (g < 2097152)      { in = x;  out = xh;             idx = g; }
  else if (g < 2359296) { in = wq; out = wcat;           idx = g - 2097152; }
  else if (g < 2621440) { in = wk; out = wcat + 1048576; idx = g - 2359296; }
  else if (g < 2883584) { in = wv; out = wcat + 2097152; idx = g - 2621440; }
  else                  { in = wo; out = woh;            idx = g - 2883584; }
  float4 v = ((const float4*)in)[idx];
  f16x4 o;
  o[0] = (_Float16)v.x; o[1] = (_Float16)v.y; o[2] = (_Float16)v.z; o[3] = (_Float16)v.w;
  ((f16x4*)out)[idx] = o;
}

// ---------------- Q/K projection (swapped epilogue, f16x4 stores) ----------------
// grid (16, 64): bx<8 -> Qh, else Kh.
__global__ __launch_bounds__(256) void qk_gemm(
    const _Float16* __restrict__ A, const _Float16* __restrict__ B,
    _Float16* __restrict__ Qh, _Float16* __restrict__ Kh) {
  int bx = blockIdx.x, by = blockIdx.y;
  const _Float16* Ab = A + (long long)by * 128 * 1024;
  const _Float16* Bb = B + (long long)bx * 128 * 1024;
  GEMM_PROLOGUE(Ab, 1024, Bb, 1024)
  GEMM_KLOOP(1024, 1024, 1024, true)

  _Float16* C = (bx < 8) ? Qh : Kh;
  int m0 = by * 128 + wm + l16;
  int n0 = (bx & 7) * 128 + wn + quad * 4;
  #pragma unroll
  for (int i = 0; i < 4; i++)
    #pragma unroll
    for (int j = 0; j < 4; j++) {
      f16x4 pk;
      #pragma unroll
      for (int r = 0; r < 4; r++) pk[r] = (_Float16)acc[i][j][r];
      *(f16x4*)(C + (long long)(m0 + i * 16) * 1024 + (n0 + j * 16)) = pk;
    }
}

// ---------------- V projection (normal order, transposed Vt stores) ----------------
// grid (8, 64): Vt[b][d=1024][s=2048]
__global__ __launch_bounds__(256) void v_gemm(
    const _Float16* __restrict__ A, const _Float16* __restrict__ B,
    _Float16* __restrict__ Vt) {
  int bx = blockIdx.x, by = blockIdx.y;
  const _Float16* Ab = A + (long long)by * 128 * 1024;
  const _Float16* Bb = B + (long long)bx * 128 * 1024;
  GEMM_PROLOGUE(Ab, 1024, Bb, 1024)
  GEMM_KLOOP(1024, 1024, 1024, false)

  int m0 = by * 128 + wm + quad * 4;
  int d0 = bx * 128 + wn + l16;
  #pragma unroll
  for (int i = 0; i < 4; i++) {
    long long mm = m0 + i * 16;
    long long b = mm >> 11;
    long long s = mm & 2047;
    #pragma unroll
    for (int j = 0; j < 4; j++) {
      f16x4 pk;
      #pragma unroll
      for (int r = 0; r < 4; r++) pk[r] = (_Float16)acc[i][j][r];
      *(f16x4*)(Vt + (b << 21) + (long long)(d0 + j * 16) * 2048 + s) = pk;
    }
  }
}

// ---------------- scores GEMM + fused softmax stats (swapped epilogue) ----------------
// u = s - m_t fp16 into S[bz][2048][2048]; stats[bz][row][bx] = {m_t, l_t}.
__global__ __launch_bounds__(256) void scores_gemm(
    const _Float16* __restrict__ Qh, const _Float16* __restrict__ Kh,
    _Float16* __restrict__ S, float2* __restrict__ stats) {
  int bx = blockIdx.x, by = blockIdx.y, bz = blockIdx.z;
  if (bx > by) return;
  const _Float16* Ab = Qh + (long long)bz * 2097152 + (long long)by * 128 * 1024;
  const _Float16* Bb = Kh + (long long)bz * 2097152 + (long long)bx * 128 * 1024;
  __shared__ float redM[128];
  __shared__ float redL[128];
  GEMM_PROLOGUE(Ab, 1024, Bb, 1024)
  GEMM_KLOOP(1024, 1024, 1024, true)

  // swapped layout: m = wm + i*16 + l16, n = wn + j*16 + quad*4 + r
  bool diag = (bx == by);
  int rloc = wm + l16;       // + i*16
  int cloc = wn + quad * 4;  // + j*16 + r

  // row max (this wave's 64-col half), masked on diag tile
  float mloc[4];
  #pragma unroll
  for (int i = 0; i < 4; i++) {
    float mx = -3.0e38f;
    #pragma unroll
    for (int j = 0; j < 4; j++)
      #pragma unroll
      for (int r = 0; r < 4; r++) {
        bool ok = !diag || (cloc + j * 16 + r <= rloc + i * 16);
        mx = ok ? fmaxf(mx, acc[i][j][r]) : mx;
      }
    mx = fmaxf(mx, __shfl_xor(mx, 16));
    mx = fmaxf(mx, __shfl_xor(mx, 32));
    mloc[i] = mx;
  }
  __syncthreads();
  if (wn && quad == 0) {
    #pragma unroll
    for (int i = 0; i < 4; i++) redM[rloc + i * 16] = mloc[i];
  }
  __syncthreads();
  if (!wn) {
    #pragma unroll
    for (int i = 0; i < 4; i++) mloc[i] = fmaxf(mloc[i], redM[rloc + i * 16]);
  }
  __syncthreads();
  if (!wn && quad == 0) {
    #pragma unroll
    for (int i = 0; i < 4; i++) redM[rloc + i * 16] = mloc[i];
  }
  __syncthreads();
  float mfin[4];
  #pragma unroll
  for (int i = 0; i < 4; i++) mfin[i] = redM[rloc + i * 16];

  // sum of exp(s - m_t) over valid cols
  float lloc[4];
  #pragma unroll
  for (int i = 0; i < 4; i++) {
    float sum = 0.f;
    #pragma unroll
    for (int j = 0; j < 4; j++)
      #pragma unroll
      for (int r = 0; r < 4; r++) {
        bool ok = !diag || (cloc + j * 16 + r <= rloc + i * 16);
        float e = __expf(acc[i][j][r] - mfin[i]);
        sum += ok ? e : 0.f;
      }
    sum += __shfl_xor(sum, 16);
    sum += __shfl_xor(sum, 32);
    lloc[i] = sum;
  }
  if (wn && quad == 0) {
    #pragma unroll
    for (int i = 0; i < 4; i++) redL[rloc + i * 16] = lloc[i];
  }
  __syncthreads();
  if (!wn && quad == 0) {
    #pragma unroll
    for (int i = 0; i < 4; i++) {
      int rl = rloc + i * 16;
      float lt = lloc[i] + redL[rl];
      stats[((long long)bz * 2048 + by * 128 + rl) * 16 + bx] =
          make_float2(mfin[i], lt);
    }
  }

  // store u = s - m_t as f16x4 (n-contiguous)
  _Float16* Sb = S + (long long)bz * 4194304;
  int gm = by * 128 + rloc;
  int gn = bx * 128 + cloc;
  #pragma unroll
  for (int i = 0; i < 4; i++)
    #pragma unroll
    for (int j = 0; j < 4; j++) {
      f16x4 u;
      #pragma unroll
      for (int r = 0; r < 4; r++) u[r] = (_Float16)(acc[i][j][r] - mfin[i]);
      *(f16x4*)(Sb + (long long)(gm + i * 16) * 2048 + (gn + j * 16)) = u;
    }
}

// ---------------- normalize: u -> p in place ----------------
__global__ __launch_bounds__(256) void normalize_p(_Float16* __restrict__ S,
                                                   const float2* __restrict__ stats) {
  int g = blockIdx.x;
  int bz = g >> 11, row = g & 2047;
  int nt = (row >> 7) + 1;
  _Float16* srow = S + ((long long)bz * 2048 + row) * 2048;
  const float2* st = stats + ((long long)bz * 2048 + row) * 16;
  __shared__ float sh_invl;
  __shared__ float shd[16];
  int t = threadIdx.x;
  if (t < 16) {
    float2 p = (t < nt) ? st[t] : make_float2(-3.0e38f, 0.f);
    float m = p.x;
    #pragma unroll
    for (int d = 1; d < 16; d <<= 1) m = fmaxf(m, __shfl_xor(m, d));
    float term = p.y * __expf(p.x - m);
    #pragma unroll
    for (int d = 1; d < 16; d <<= 1) term += __shfl_xor(term, d);
    shd[t] = p.x - m;
    if (t == 0) sh_invl = 1.0f / term;
  }
  __syncthreads();
  float invl = sh_invl;
  int Lp = nt << 7;
  for (int c = t; (c << 3) < Lp; c += 256) {
    float dt = shd[c >> 4];
    f16x8 v = ((f16x8*)srow)[c];
    f16x8 o;
    int col0 = c << 3;
    #pragma unroll
    for (int e = 0; e < 8; e++) {
      float u = (float)v[e];
      float pe = __expf(u + dt) * invl;
      o[e] = (col0 + e <= row) ? (_Float16)pe : (_Float16)0.f;
    }
    ((f16x8*)srow)[c] = o;
  }
}

// ---------------- split-K PV GEMM (swapped epilogue) ----------------
// grid (8, 24, 4). cy<8: full row (k<=1024) -> Oh fp16 direct.
// cy>=8: chunked -> fp32 partials P0/P1 with float4 stores.
__global__ __launch_bounds__(256) void pv_splitk(
    const _Float16* __restrict__ P,   // S fp16 [bz][2048][2048]
    const _Float16* __restrict__ Vt,  // [b][1024][2048]
    float* __restrict__ P0, float* __restrict__ P1,
    _Float16* __restrict__ Oh) {
  int bx = blockIdx.x, cy = blockIdx.y, bz = blockIdx.z;
  int by, c;
  if (cy < 8) { by = cy; c = 0; }
  else { int q = cy - 8; by = 8 + (q >> 1); c = q & 1; }
  int kmax = (by + 1) * 128;
  int k0 = c * 1024;
  int klen = min(kmax, k0 + 1024) - k0;

  const _Float16* Ab = P + (long long)bz * 4194304LL + (long long)by * 128 * 2048 + k0;
  const _Float16* Bb = Vt + (long long)bz * 2097152LL + (long long)bx * 128 * 2048 + k0;
  GEMM_PROLOGUE(Ab, 2048, Bb, 2048)
  GEMM_KLOOP(2048, 2048, klen, true)

  int m0 = by * 128 + wm + l16;
  int n0 = bx * 128 + wn + quad * 4;

  if (c == 0 && by < 8) {
    _Float16* C = Oh + (long long)bz * 2097152LL;
    #pragma unroll
    for (int i = 0; i < 4; i++)
      #pragma unroll
      for (int j = 0; j < 4; j++) {
        f16x4 pk;
        #pragma unroll
        for (int r = 0; r < 4; r++) pk[r] = (_Float16)acc[i][j][r];
        *(f16x4*)(C + (long long)(m0 + i * 16) * 1024 + (n0 + j * 16)) = pk;
      }
  } else if (c == 0) {
    float* C = P0 + (long long)bz * 2097152LL;
    #pragma unroll
    for (int i = 0; i < 4; i++)
      #pragma unroll
      for (int j = 0; j < 4; j++)
        *(f32x4*)(C + (long long)(m0 + i * 16) * 1024 + (n0 + j * 16)) = acc[i][j];
  } else {
    float* C = P1 + (long long)bz * 1048576LL;
    int mr = m0 - 1024;
    #pragma unroll
    for (int i = 0; i < 4; i++)
      #pragma unroll
      for (int j = 0; j < 4; j++)
        *(f32x4*)(C + (long long)(mr + i * 16) * 1024 + (n0 + j * 16)) = acc[i][j];
  }
}

// ---------------- PV reduce, upper 1024 rows only ----------------
__global__ __launch_bounds__(256) void pv_reduce(const float* __restrict__ P0,
                                                 const float* __restrict__ P1,
                                                 _Float16* __restrict__ Oh) {
  int i = blockIdx.x * 256 + threadIdx.x;
  if (i >= 1048576) return;
  int f4 = i;
  int bz = f4 >> 18;
  int loc = f4 & 262143;
  long long p0i = (long long)bz * 524288 + 262144 + loc;
  float4 v = ((const float4*)P0)[p0i];
  float4 w = ((const float4*)P1)[f4];
  v.x += w.x; v.y += w.y; v.z += w.z; v.w += w.w;
  f16x4 o;
  o[0] = (_Float16)v.x; o[1] = (_Float16)v.y; o[2] = (_Float16)v.z; o[3] = (_Float16)v.w;
  ((f16x4*)Oh)[p0i] = o;
}

// ---------------- output projection (+bias, fp32, swapped float4 stores) ----------------
__global__ __launch_bounds__(256) void oproj_gemm(
    const _Float16* __restrict__ A, const _Float16* __restrict__ B,
    float* __restrict__ C, const float* __restrict__ bias) {
  int bx = blockIdx.x, by = blockIdx.y;
  const _Float16* Ab = A + (long long)by * 128 * 1024;
  const _Float16* Bb = B + (long long)bx * 128 * 1024;
  GEMM_PROLOGUE(Ab, 1024, Bb, 1024)
  GEMM_KLOOP(1024, 1024, 1024, true)

  int m0 = by * 128 + wm + l16;
  int n0 = bx * 128 + wn + quad * 4;
  #pragma unroll
  for (int j = 0; j < 4; j++) {
    float4 b4 = *(const float4*)(bias + n0 + j * 16);
    #pragma unroll
    for (int i = 0; i < 4; i++) {
      f32x4 v = acc[i][j];
      v[0] += b4.x; v[1] += b4.y; v[2] += b4.z; v[3] += b4.w;
      *(f32x4*)(C + (long long)(m0 + i * 16) * 1024 + (n0 + j * 16)) = v;
    }
  }
}

// ---------------- workspace layout (bytes) ----------------
// xh   : 0          16,777,216   -> P1 alias during PV
// Wcat : 16777216    6,291,456
// Woh  : 23068672    2,097,152
// Qh   : 25165824   16,777,216   -> P0 alias (with Kh) during PV
// Kh   : 41943040   16,777,216
// Vt   : 58720256   16,777,216
// Oh   : 75497472   16,777,216
// Sb   : 92274688   33,554,432   fp16 u/p [4][2048][2048]
// stats: 125829120   1,048,576   float2 [4][2048][16]
// total: 126,877,696

extern "C" void kernel_launch(void* const* d_in, const int* in_sizes, int n_in,
                              void* d_out, int out_size, void* d_ws, size_t ws_size,
                              hipStream_t stream) {
  const float* x  = (const float*)d_in[0];
  const float* Wq = (const float*)d_in[1];
  const float* Wk = (const float*)d_in[2];
  const float* Wv = (const float*)d_in[3];
  const float* Wo = (const float*)d_in[4];
  const float* bO = (const float*)d_in[5];

  char* ws = (char*)d_ws;
  _Float16* xh   = (_Float16*)(ws + 0);
  _Float16* Wcat = (_Float16*)(ws + 16777216);
  _Float16* Woh  = (_Float16*)(ws + 23068672);
  _Float16* Qh   = (_Float16*)(ws + 25165824);
  _Float16* Kh   = (_Float16*)(ws + 41943040);
  _Float16* Vt   = (_Float16*)(ws + 58720256);
  _Float16* Oh   = (_Float16*)(ws + 75497472);
  _Float16* Sb   = (_Float16*)(ws + 92274688);
  float2*   stats= (float2*)  (ws + 125829120);
  float*    P0   = (float*)   (ws + 25165824);  // aliases Qh+Kh (dead by PV)
  float*    P1   = (float*)   (ws + 0);         // aliases xh (dead by PV)

  dim3 blk(256);

  cvt_all<<<12288, blk, 0, stream>>>(x, Wq, Wk, Wv, Wo, xh, Wcat, Woh);

  // Q/K projection (swapped, vectorized stores) + V projection (transposed Vt)
  qk_gemm<<<dim3(16, 64, 1), blk, 0, stream>>>(xh, Wcat, Qh, Kh);
  v_gemm<<<dim3(8, 64, 1), blk, 0, stream>>>(xh, Wcat + 2097152, Vt);

  // scores + fused softmax statistics (fp16 u output)
  scores_gemm<<<dim3(16, 16, 4), blk, 0, stream>>>(Qh, Kh, Sb, stats);

  // combine stats + normalize u -> p in place
  normalize_p<<<8192, blk, 0, stream>>>(Sb, stats);

  // O = P @ Vt^T with split-K
  pv_splitk<<<dim3(8, 24, 4), blk, 0, stream>>>(Sb, Vt, P0, P1, Oh);
  pv_reduce<<<4096, blk, 0, stream>>>(P0, P1, Oh);

  // out = O @ Wo^T + b_O
  oproj_gemm<<<dim3(8, 64, 1), blk, 0, stream>>>(Oh, Woh, (float*)d_out, bO);
}

// Round 6
// 301.129 us; speedup vs baseline: 1.0765x; 1.0765x over previous
//
#include <hip/hip_runtime.h>
#include <cstdint>

typedef _Float16 f16x8 __attribute__((ext_vector_type(8)));
typedef _Float16 f16x4 __attribute__((ext_vector_type(4)));
typedef float    f32x4 __attribute__((ext_vector_type(4)));

#define AS1 __attribute__((address_space(1)))
#define AS3 __attribute__((address_space(3)))

__device__ __forceinline__ void load16_lds(const void* g, void* l) {
  __builtin_amdgcn_global_load_lds((AS1 void*)g, (AS3 void*)l, 16, 0, 0);
}

// 128x128-tile K-loop machinery (m97 structure).
// SWAPPED variant: acc[i][j][r] = C[m = wm+16i+l16][n = wn+16j+quad*4+r]
// NORMAL  variant: acc[i][j][r] = C[m = wm+16i+quad*4+r][n = wn+16j+l16]
#define GEMM_PROLOGUE(Ab, lda, Bb, ldb)                                   \
  __shared__ _Float16 lA[128 * 32];                                       \
  __shared__ _Float16 lB[128 * 32];                                       \
  int tid = threadIdx.x;                                                  \
  int r0 = tid >> 2;                                                      \
  int c0 = (tid & 3) * 8;                                                 \
  const _Float16* ga0 = Ab + (long long)r0 * lda + c0;                    \
  const _Float16* ga1 = Ab + (long long)(r0 + 64) * lda + c0;             \
  const _Float16* gb0 = Bb + (long long)r0 * ldb + c0;                    \
  const _Float16* gb1 = Bb + (long long)(r0 + 64) * ldb + c0;             \
  _Float16* la0 = lA + tid * 8;                                           \
  _Float16* la1 = lA + 2048 + tid * 8;                                    \
  _Float16* lb0 = lB + tid * 8;                                           \
  _Float16* lb1 = lB + 2048 + tid * 8;                                    \
  f32x4 acc[4][4] = {};                                                   \
  int lane = tid & 63;                                                    \
  int wv = tid >> 6;                                                      \
  int wm = (wv & 1) * 64, wn = (wv >> 1) * 64;                            \
  int l16 = lane & 15, quad = lane >> 4;                                  \
  const _Float16* raBase = lA + (wm + l16) * 32 + quad * 8;               \
  const _Float16* rbBase = lB + (wn + l16) * 32 + quad * 8;

#define GEMM_KLOOP(lda, ldb, KLEN, SWAP)                                  \
  for (int kb = 0; kb < (KLEN); kb += 32) {                               \
    __syncthreads();                                                      \
    load16_lds(ga0, la0);                                                 \
    load16_lds(ga1, la1);                                                 \
    load16_lds(gb0, lb0);                                                 \
    load16_lds(gb1, lb1);                                                 \
    ga0 += 32; ga1 += 32; gb0 += 32; gb1 += 32;                           \
    __syncthreads();                                                      \
    f16x8 af[4], bfr[4];                                                  \
    _Pragma("unroll")                                                     \
    for (int i = 0; i < 4; i++) af[i] = *(const f16x8*)(raBase + i * 512);\
    _Pragma("unroll")                                                     \
    for (int j = 0; j < 4; j++) bfr[j] = *(const f16x8*)(rbBase + j * 512);\
    _Pragma("unroll")                                                     \
    for (int i = 0; i < 4; i++)                                           \
      _Pragma("unroll")                                                   \
      for (int j = 0; j < 4; j++)                                         \
        acc[i][j] = (SWAP)                                                \
          ? __builtin_amdgcn_mfma_f32_16x16x32_f16(bfr[j], af[i], acc[i][j], 0, 0, 0) \
          : __builtin_amdgcn_mfma_f32_16x16x32_f16(af[i], bfr[j], acc[i][j], 0, 0, 0);\
  }

// ---------------- fused fp32 -> fp16 convert for all 5 inputs ----------------
__global__ __launch_bounds__(256) void cvt_all(
    const float* __restrict__ x, const float* __restrict__ wq,
    const float* __restrict__ wk, const float* __restrict__ wv,
    const float* __restrict__ wo,
    _Float16* __restrict__ xh, _Float16* __restrict__ wcat,
    _Float16* __restrict__ woh) {
  long long g = (long long)blockIdx.x * 256 + threadIdx.x;
  const float* in; _Float16* out; long long idx;
  if (g < 2097152)      { in = x;  out = xh;             idx = g; }
  else if (g < 2359296) { in = wq; out = wcat;           idx = g - 2097152; }
  else if (g < 2621440) { in = wk; out = wcat + 1048576; idx = g - 2359296; }
  else if (g < 2883584) { in = wv; out = wcat + 2097152; idx = g - 2621440; }
  else                  { in = wo; out = woh;            idx = g - 2883584; }
  float4 v = ((const float4*)in)[idx];
  f16x4 o;
  o[0] = (_Float16)v.x; o[1] = (_Float16)v.y; o[2] = (_Float16)v.z; o[3] = (_Float16)v.w;
  ((f16x4*)out)[idx] = o;
}

// ---------------- fused QKV projection (single launch) ----------------
// grid (24, 64): bx<8 -> Qh (swapped), bx<16 -> Kh (swapped), else Vt (normal,
// transposed stores [b][d][s]).
__global__ __launch_bounds__(256) void qkv_gemm(
    const _Float16* __restrict__ A, const _Float16* __restrict__ B,
    _Float16* __restrict__ Qh, _Float16* __restrict__ Kh, _Float16* __restrict__ Vt) {
  int bx = blockIdx.x, by = blockIdx.y;
  const _Float16* Ab = A + (long long)by * 128 * 1024;
  const _Float16* Bb = B + (long long)bx * 128 * 1024;
  GEMM_PROLOGUE(Ab, 1024, Bb, 1024)

  if (bx < 16) {
    GEMM_KLOOP(1024, 1024, 1024, true)
    _Float16* C = (bx < 8) ? Qh : Kh;
    int m0 = by * 128 + wm + l16;
    int n0 = (bx & 7) * 128 + wn + quad * 4;
    #pragma unroll
    for (int i = 0; i < 4; i++)
      #pragma unroll
      for (int j = 0; j < 4; j++) {
        f16x4 pk;
        #pragma unroll
        for (int r = 0; r < 4; r++) pk[r] = (_Float16)acc[i][j][r];
        *(f16x4*)(C + (long long)(m0 + i * 16) * 1024 + (n0 + j * 16)) = pk;
      }
  } else {
    GEMM_KLOOP(1024, 1024, 1024, false)
    int m0 = by * 128 + wm + quad * 4;
    int d0 = (bx - 16) * 128 + wn + l16;
    #pragma unroll
    for (int i = 0; i < 4; i++) {
      long long mm = m0 + i * 16;
      long long b = mm >> 11;
      long long s = mm & 2047;
      #pragma unroll
      for (int j = 0; j < 4; j++) {
        f16x4 pk;
        #pragma unroll
        for (int r = 0; r < 4; r++) pk[r] = (_Float16)acc[i][j][r];
        *(f16x4*)(Vt + (b << 21) + (long long)(d0 + j * 16) * 2048 + s) = pk;
      }
    }
  }
}

// ---------------- scores GEMM, 64x128 tiles, compact causal grid ----------------
// grid (272, 4): linear lower-tri enumeration of (by64, bx128) with
// bx <= by>>1. 4 waves side-by-side in n (each 64m x 32n). Swapped epilogue:
// acc[i][j][r] = S[m = 16i+l16][n = wn+16j+quad*4+r], i<4, j<2.
// Writes u = s - m_t fp16 into S[bz][2048][2048]; stats[bz][row][bx]={m_t,l_t}.
__global__ __launch_bounds__(256) void scores_gemm(
    const _Float16* __restrict__ Qh, const _Float16* __restrict__ Kh,
    _Float16* __restrict__ S, float2* __restrict__ stats) {
  int t = blockIdx.x, bz = blockIdx.y;
  int g = (int)((__builtin_sqrtf(4.0f * t + 1.0f) - 1.0f) * 0.5f);
  while ((g + 1) * (g + 2) <= t) g++;
  while (g * (g + 1) > t) g--;
  int rem = t - g * (g + 1);
  int by = 2 * g + (rem > g ? 1 : 0);     // 64-row tile index, 0..31
  int bxt = (rem > g) ? rem - (g + 1) : rem;  // 128-col tile index, 0..g
  bool diag = (bxt == g);

  const _Float16* Ab = Qh + (long long)bz * 2097152 + (long long)by * 64 * 1024;
  const _Float16* Bb = Kh + (long long)bz * 2097152 + (long long)bxt * 128 * 1024;

  __shared__ _Float16 lA[64 * 32];
  __shared__ _Float16 lB[128 * 32];
  __shared__ float redM[4][64];
  __shared__ float redL[4][64];

  int tid = threadIdx.x;
  int r0 = tid >> 2;
  int c0 = (tid & 3) * 8;
  const _Float16* ga0 = Ab + (long long)r0 * 1024 + c0;
  const _Float16* gb0 = Bb + (long long)r0 * 1024 + c0;
  const _Float16* gb1 = Bb + (long long)(r0 + 64) * 1024 + c0;
  _Float16* la0 = lA + tid * 8;
  _Float16* lb0 = lB + tid * 8;
  _Float16* lb1 = lB + 2048 + tid * 8;

  f32x4 acc[4][2] = {};
  int lane = tid & 63;
  int wv = tid >> 6;
  int wn = wv * 32;
  int l16 = lane & 15, quad = lane >> 4;
  const _Float16* raBase = lA + l16 * 32 + quad * 8;
  const _Float16* rbBase = lB + (wn + l16) * 32 + quad * 8;

  for (int kb = 0; kb < 1024; kb += 32) {
    __syncthreads();
    load16_lds(ga0, la0);
    load16_lds(gb0, lb0);
    load16_lds(gb1, lb1);
    ga0 += 32; gb0 += 32; gb1 += 32;
    __syncthreads();
    f16x8 af[4], bfr[2];
    #pragma unroll
    for (int i = 0; i < 4; i++) af[i] = *(const f16x8*)(raBase + i * 512);
    #pragma unroll
    for (int j = 0; j < 2; j++) bfr[j] = *(const f16x8*)(rbBase + j * 512);
    #pragma unroll
    for (int i = 0; i < 4; i++)
      #pragma unroll
      for (int j = 0; j < 2; j++)
        acc[i][j] = __builtin_amdgcn_mfma_f32_16x16x32_f16(bfr[j], af[i], acc[i][j], 0, 0, 0);
  }

  // rows: rl = 16i + l16 (local), grow = by*64 + rl
  // cols: cl = wn + 16j + quad*4 + r (local), gcol = bxt*128 + cl
  int rowBase = by * 64;
  int colBase = bxt * 128;

  // per-wave row max (masked on diagonal tile)
  float mloc[4];
  #pragma unroll
  for (int i = 0; i < 4; i++) {
    int grow = rowBase + 16 * i + l16;
    float mx = -3.0e38f;
    #pragma unroll
    for (int j = 0; j < 2; j++)
      #pragma unroll
      for (int r = 0; r < 4; r++) {
        bool ok = !diag || (colBase + wn + 16 * j + quad * 4 + r <= grow);
        mx = ok ? fmaxf(mx, acc[i][j][r]) : mx;
      }
    mx = fmaxf(mx, __shfl_xor(mx, 16));
    mx = fmaxf(mx, __shfl_xor(mx, 32));
    mloc[i] = mx;
  }
  if (quad == 0) {
    #pragma unroll
    for (int i = 0; i < 4; i++) redM[wv][16 * i + l16] = mloc[i];
  }
  __syncthreads();
  float mfin[4];
  #pragma unroll
  for (int i = 0; i < 4; i++) {
    int rl = 16 * i + l16;
    mfin[i] = fmaxf(fmaxf(redM[0][rl], redM[1][rl]), fmaxf(redM[2][rl], redM[3][rl]));
  }

  // per-wave sum of exp(s - m_t) (masked)
  float lloc[4];
  #pragma unroll
  for (int i = 0; i < 4; i++) {
    int grow = rowBase + 16 * i + l16;
    float sum = 0.f;
    #pragma unroll
    for (int j = 0; j < 2; j++)
      #pragma unroll
      for (int r = 0; r < 4; r++) {
        bool ok = !diag || (colBase + wn + 16 * j + quad * 4 + r <= grow);
        float e = __expf(acc[i][j][r] - mfin[i]);
        sum += ok ? e : 0.f;
      }
    sum += __shfl_xor(sum, 16);
    sum += __shfl_xor(sum, 32);
    lloc[i] = sum;
  }
  if (quad == 0) {
    #pragma unroll
    for (int i = 0; i < 4; i++) redL[wv][16 * i + l16] = lloc[i];
  }
  __syncthreads();
  if (wv == 0 && quad == 0) {
    #pragma unroll
    for (int i = 0; i < 4; i++) {
      int rl = 16 * i + l16;
      float lt = redL[0][rl] + redL[1][rl] + redL[2][rl] + redL[3][rl];
      stats[((long long)bz * 2048 + rowBase + rl) * 16 + bxt] =
          make_float2(mfin[i], lt);
    }
  }

  // store u = s - m_t as f16x4 (n-contiguous)
  _Float16* Sb = S + (long long)bz * 4194304;
  #pragma unroll
  for (int i = 0; i < 4; i++) {
    long long grow = rowBase + 16 * i + l16;
    #pragma unroll
    for (int j = 0; j < 2; j++) {
      f16x4 u;
      #pragma unroll
      for (int r = 0; r < 4; r++) u[r] = (_Float16)(acc[i][j][r] - mfin[i]);
      *(f16x4*)(Sb + grow * 2048 + (colBase + wn + 16 * j + quad * 4)) = u;
    }
  }
}

// ---------------- normalize: u -> p in place ----------------
__global__ __launch_bounds__(256) void normalize_p(_Float16* __restrict__ S,
                                                   const float2* __restrict__ stats) {
  int g = blockIdx.x;
  int bz = g >> 11, row = g & 2047;
  int nt = (row >> 7) + 1;
  _Float16* srow = S + ((long long)bz * 2048 + row) * 2048;
  const float2* st = stats + ((long long)bz * 2048 + row) * 16;
  __shared__ float sh_invl;
  __shared__ float shd[16];
  int t = threadIdx.x;
  if (t < 16) {
    float2 p = (t < nt) ? st[t] : make_float2(-3.0e38f, 0.f);
    float m = p.x;
    #pragma unroll
    for (int d = 1; d < 16; d <<= 1) m = fmaxf(m, __shfl_xor(m, d));
    float term = p.y * __expf(p.x - m);
    #pragma unroll
    for (int d = 1; d < 16; d <<= 1) term += __shfl_xor(term, d);
    shd[t] = p.x - m;
    if (t == 0) sh_invl = 1.0f / term;
  }
  __syncthreads();
  float invl = sh_invl;
  int Lp = nt << 7;
  for (int c = t; (c << 3) < Lp; c += 256) {
    float dt = shd[c >> 4];
    f16x8 v = ((f16x8*)srow)[c];
    f16x8 o;
    int col0 = c << 3;
    #pragma unroll
    for (int e = 0; e < 8; e++) {
      float u = (float)v[e];
      float pe = __expf(u + dt) * invl;
      o[e] = (col0 + e <= row) ? (_Float16)pe : (_Float16)0.f;
    }
    ((f16x8*)srow)[c] = o;
  }
}

// ---------------- split-K PV GEMM (swapped epilogue) ----------------
// grid (8, 24, 4). cy<8: full row (k<=1024) -> Oh fp16 direct.
// cy>=8: chunked -> fp32 partials P0/P1 with float4 stores.
__global__ __launch_bounds__(256) void pv_splitk(
    const _Float16* __restrict__ P,   // S fp16 [bz][2048][2048]
    const _Float16* __restrict__ Vt,  // [b][1024][2048]
    float* __restrict__ P0, float* __restrict__ P1,
    _Float16* __restrict__ Oh) {
  int bx = blockIdx.x, cy = blockIdx.y, bz = blockIdx.z;
  int by, c;
  if (cy < 8) { by = cy; c = 0; }
  else { int q = cy - 8; by = 8 + (q >> 1); c = q & 1; }
  int kmax = (by + 1) * 128;
  int k0 = c * 1024;
  int klen = min(kmax, k0 + 1024) - k0;

  const _Float16* Ab = P + (long long)bz * 4194304LL + (long long)by * 128 * 2048 + k0;
  const _Float16* Bb = Vt + (long long)bz * 2097152LL + (long long)bx * 128 * 2048 + k0;
  GEMM_PROLOGUE(Ab, 2048, Bb, 2048)
  GEMM_KLOOP(2048, 2048, klen, true)

  int m0 = by * 128 + wm + l16;
  int n0 = bx * 128 + wn + quad * 4;

  if (c == 0 && by < 8) {
    _Float16* C = Oh + (long long)bz * 2097152LL;
    #pragma unroll
    for (int i = 0; i < 4; i++)
      #pragma unroll
      for (int j = 0; j < 4; j++) {
        f16x4 pk;
        #pragma unroll
        for (int r = 0; r < 4; r++) pk[r] = (_Float16)acc[i][j][r];
        *(f16x4*)(C + (long long)(m0 + i * 16) * 1024 + (n0 + j * 16)) = pk;
      }
  } else if (c == 0) {
    float* C = P0 + (long long)bz * 2097152LL;
    #pragma unroll
    for (int i = 0; i < 4; i++)
      #pragma unroll
      for (int j = 0; j < 4; j++)
        *(f32x4*)(C + (long long)(m0 + i * 16) * 1024 + (n0 + j * 16)) = acc[i][j];
  } else {
    float* C = P1 + (long long)bz * 1048576LL;
    int mr = m0 - 1024;
    #pragma unroll
    for (int i = 0; i < 4; i++)
      #pragma unroll
      for (int j = 0; j < 4; j++)
        *(f32x4*)(C + (long long)(mr + i * 16) * 1024 + (n0 + j * 16)) = acc[i][j];
  }
}

// ---------------- PV reduce, upper 1024 rows only ----------------
__global__ __launch_bounds__(256) void pv_reduce(const float* __restrict__ P0,
                                                 const float* __restrict__ P1,
                                                 _Float16* __restrict__ Oh) {
  int i = blockIdx.x * 256 + threadIdx.x;
  if (i >= 1048576) return;
  int f4 = i;
  int bz = f4 >> 18;
  int loc = f4 & 262143;
  long long p0i = (long long)bz * 524288 + 262144 + loc;
  float4 v = ((const float4*)P0)[p0i];
  float4 w = ((const float4*)P1)[f4];
  v.x += w.x; v.y += w.y; v.z += w.z; v.w += w.w;
  f16x4 o;
  o[0] = (_Float16)v.x; o[1] = (_Float16)v.y; o[2] = (_Float16)v.z; o[3] = (_Float16)v.w;
  ((f16x4*)Oh)[p0i] = o;
}

// ---------------- output projection (+bias, fp32, swapped float4 stores) ----------------
__global__ __launch_bounds__(256) void oproj_gemm(
    const _Float16* __restrict__ A, const _Float16* __restrict__ B,
    float* __restrict__ C, const float* __restrict__ bias) {
  int bx = blockIdx.x, by = blockIdx.y;
  const _Float16* Ab = A + (long long)by * 128 * 1024;
  const _Float16* Bb = B + (long long)bx * 128 * 1024;
  GEMM_PROLOGUE(Ab, 1024, Bb, 1024)
  GEMM_KLOOP(1024, 1024, 1024, true)

  int m0 = by * 128 + wm + l16;
  int n0 = bx * 128 + wn + quad * 4;
  #pragma unroll
  for (int j = 0; j < 4; j++) {
    float4 b4 = *(const float4*)(bias + n0 + j * 16);
    #pragma unroll
    for (int i = 0; i < 4; i++) {
      f32x4 v = acc[i][j];
      v[0] += b4.x; v[1] += b4.y; v[2] += b4.z; v[3] += b4.w;
      *(f32x4*)(C + (long long)(m0 + i * 16) * 1024 + (n0 + j * 16)) = v;
    }
  }
}

// ---------------- workspace layout (bytes) ----------------
// xh   : 0          16,777,216   -> P1 alias during PV
// Wcat : 16777216    6,291,456
// Woh  : 23068672    2,097,152
// Qh   : 25165824   16,777,216   -> P0 alias (with Kh) during PV
// Kh   : 41943040   16,777,216
// Vt   : 58720256   16,777,216
// Oh   : 75497472   16,777,216
// Sb   : 92274688   33,554,432   fp16 u/p [4][2048][2048]
// stats: 125829120   1,048,576   float2 [4][2048][16]
// total: 126,877,696

extern "C" void kernel_launch(void* const* d_in, const int* in_sizes, int n_in,
                              void* d_out, int out_size, void* d_ws, size_t ws_size,
                              hipStream_t stream) {
  const float* x  = (const float*)d_in[0];
  const float* Wq = (const float*)d_in[1];
  const float* Wk = (const float*)d_in[2];
  const float* Wv = (const float*)d_in[3];
  const float* Wo = (const float*)d_in[4];
  const float* bO = (const float*)d_in[5];

  char* ws = (char*)d_ws;
  _Float16* xh   = (_Float16*)(ws + 0);
  _Float16* Wcat = (_Float16*)(ws + 16777216);
  _Float16* Woh  = (_Float16*)(ws + 23068672);
  _Float16* Qh   = (_Float16*)(ws + 25165824);
  _Float16* Kh   = (_Float16*)(ws + 41943040);
  _Float16* Vt   = (_Float16*)(ws + 58720256);
  _Float16* Oh   = (_Float16*)(ws + 75497472);
  _Float16* Sb   = (_Float16*)(ws + 92274688);
  float2*   stats= (float2*)  (ws + 125829120);
  float*    P0   = (float*)   (ws + 25165824);  // aliases Qh+Kh (dead by PV)
  float*    P1   = (float*)   (ws + 0);         // aliases xh (dead by PV)

  dim3 blk(256);

  cvt_all<<<12288, blk, 0, stream>>>(x, Wq, Wk, Wv, Wo, xh, Wcat, Woh);

  // fused Q/K/V projection (single launch; swapped Q/K, transposed V)
  qkv_gemm<<<dim3(24, 64, 1), blk, 0, stream>>>(xh, Wcat, Qh, Kh, Vt);

  // scores + fused softmax statistics: 64x128 tiles, compact causal grid
  scores_gemm<<<dim3(272, 4, 1), blk, 0, stream>>>(Qh, Kh, Sb, stats);

  // combine stats + normalize u -> p in place
  normalize_p<<<8192, blk, 0, stream>>>(Sb, stats);

  // O = P @ Vt^T with split-K
  pv_splitk<<<dim3(8, 24, 4), blk, 0, stream>>>(Sb, Vt, P0, P1, Oh);
  pv_reduce<<<4096, blk, 0, stream>>>(P0, P1, Oh);

  // out = O @ Wo^T + b_O
  oproj_gemm<<<dim3(8, 64, 1), blk, 0, stream>>>(Oh, Woh, (float*)d_out, bO);
}

// Round 7
// 298.238 us; speedup vs baseline: 1.0870x; 1.0097x over previous
//
#include <hip/hip_runtime.h>
#include <cstdint>

typedef _Float16 f16x8 __attribute__((ext_vector_type(8)));
typedef _Float16 f16x4 __attribute__((ext_vector_type(4)));
typedef float    f32x4 __attribute__((ext_vector_type(4)));

#define AS1 __attribute__((address_space(1)))
#define AS3 __attribute__((address_space(3)))

__device__ __forceinline__ void load16_lds(const void* g, void* l) {
  __builtin_amdgcn_global_load_lds((AS1 void*)g, (AS3 void*)l, 16, 0, 0);
}

// 128x128-tile K-loop machinery (m97 structure).
// SWAPPED variant: acc[i][j][r] = C[m = wm+16i+l16][n = wn+16j+quad*4+r]
// NORMAL  variant: acc[i][j][r] = C[m = wm+16i+quad*4+r][n = wn+16j+l16]
#define GEMM_PROLOGUE(Ab, lda, Bb, ldb)                                   \
  __shared__ _Float16 lA[128 * 32];                                       \
  __shared__ _Float16 lB[128 * 32];                                       \
  int tid = threadIdx.x;                                                  \
  int r0 = tid >> 2;                                                      \
  int c0 = (tid & 3) * 8;                                                 \
  const _Float16* ga0 = Ab + (long long)r0 * lda + c0;                    \
  const _Float16* ga1 = Ab + (long long)(r0 + 64) * lda + c0;             \
  const _Float16* gb0 = Bb + (long long)r0 * ldb + c0;                    \
  const _Float16* gb1 = Bb + (long long)(r0 + 64) * ldb + c0;             \
  _Float16* la0 = lA + tid * 8;                                           \
  _Float16* la1 = lA + 2048 + tid * 8;                                    \
  _Float16* lb0 = lB + tid * 8;                                           \
  _Float16* lb1 = lB + 2048 + tid * 8;                                    \
  f32x4 acc[4][4] = {};                                                   \
  int lane = tid & 63;                                                    \
  int wv = tid >> 6;                                                      \
  int wm = (wv & 1) * 64, wn = (wv >> 1) * 64;                            \
  int l16 = lane & 15, quad = lane >> 4;                                  \
  const _Float16* raBase = lA + (wm + l16) * 32 + quad * 8;               \
  const _Float16* rbBase = lB + (wn + l16) * 32 + quad * 8;

#define GEMM_KLOOP(lda, ldb, KLEN, SWAP)                                  \
  for (int kb = 0; kb < (KLEN); kb += 32) {                               \
    __syncthreads();                                                      \
    load16_lds(ga0, la0);                                                 \
    load16_lds(ga1, la1);                                                 \
    load16_lds(gb0, lb0);                                                 \
    load16_lds(gb1, lb1);                                                 \
    ga0 += 32; ga1 += 32; gb0 += 32; gb1 += 32;                           \
    __syncthreads();                                                      \
    f16x8 af[4], bfr[4];                                                  \
    _Pragma("unroll")                                                     \
    for (int i = 0; i < 4; i++) af[i] = *(const f16x8*)(raBase + i * 512);\
    _Pragma("unroll")                                                     \
    for (int j = 0; j < 4; j++) bfr[j] = *(const f16x8*)(rbBase + j * 512);\
    _Pragma("unroll")                                                     \
    for (int i = 0; i < 4; i++)                                           \
      _Pragma("unroll")                                                   \
      for (int j = 0; j < 4; j++)                                         \
        acc[i][j] = (SWAP)                                                \
          ? __builtin_amdgcn_mfma_f32_16x16x32_f16(bfr[j], af[i], acc[i][j], 0, 0, 0) \
          : __builtin_amdgcn_mfma_f32_16x16x32_f16(af[i], bfr[j], acc[i][j], 0, 0, 0);\
  }

// ---------------- fused fp32 -> fp16 convert for all 5 inputs ----------------
__global__ __launch_bounds__(256) void cvt_all(
    const float* __restrict__ x, const float* __restrict__ wq,
    const float* __restrict__ wk, const float* __restrict__ wv,
    const float* __restrict__ wo,
    _Float16* __restrict__ xh, _Float16* __restrict__ wcat,
    _Float16* __restrict__ woh) {
  long long g = (long long)blockIdx.x * 256 + threadIdx.x;
  const float* in; _Float16* out; long long idx;
  if (g < 2097152)      { in = x;  out = xh;             idx = g; }
  else if (g < 2359296) { in = wq; out = wcat;           idx = g - 2097152; }
  else if (g < 2621440) { in = wk; out = wcat + 1048576; idx = g - 2359296; }
  else if (g < 2883584) { in = wv; out = wcat + 2097152; idx = g - 2621440; }
  else                  { in = wo; out = woh;            idx = g - 2883584; }
  float4 v = ((const float4*)in)[idx];
  f16x4 o;
  o[0] = (_Float16)v.x; o[1] = (_Float16)v.y; o[2] = (_Float16)v.z; o[3] = (_Float16)v.w;
  ((f16x4*)out)[idx] = o;
}

// ---------------- fused QKV projection (XCD-swizzled 1-D grid) ----------------
// grid 1536: xcd = bid&7 owns bx in [xcd*3, xcd*3+3) -> per-XCD B slice
// 768 KB (L2-resident). idx>>3: sub = idx%3, by = idx/3 (A panel reused by
// the 3 adjacent blocks). bx<8 -> Qh (swapped), bx<16 -> Kh (swapped),
// else Vt (normal, transposed stores [b][d][s]).
__global__ __launch_bounds__(256) void qkv_gemm(
    const _Float16* __restrict__ A, const _Float16* __restrict__ B,
    _Float16* __restrict__ Qh, _Float16* __restrict__ Kh, _Float16* __restrict__ Vt) {
  int bid = blockIdx.x;
  int xcd = bid & 7;
  int idx = bid >> 3;       // 0..191
  int sub = idx % 3;
  int by  = idx / 3;        // 0..63
  int bx  = xcd * 3 + sub;  // 0..23

  const _Float16* Ab = A + (long long)by * 128 * 1024;
  const _Float16* Bb = B + (long long)bx * 128 * 1024;
  GEMM_PROLOGUE(Ab, 1024, Bb, 1024)

  if (bx < 16) {
    GEMM_KLOOP(1024, 1024, 1024, true)
    _Float16* C = (bx < 8) ? Qh : Kh;
    int m0 = by * 128 + wm + l16;
    int n0 = (bx & 7) * 128 + wn + quad * 4;
    #pragma unroll
    for (int i = 0; i < 4; i++)
      #pragma unroll
      for (int j = 0; j < 4; j++) {
        f16x4 pk;
        #pragma unroll
        for (int r = 0; r < 4; r++) pk[r] = (_Float16)acc[i][j][r];
        *(f16x4*)(C + (long long)(m0 + i * 16) * 1024 + (n0 + j * 16)) = pk;
      }
  } else {
    GEMM_KLOOP(1024, 1024, 1024, false)
    int m0 = by * 128 + wm + quad * 4;
    int d0 = (bx - 16) * 128 + wn + l16;
    #pragma unroll
    for (int i = 0; i < 4; i++) {
      long long mm = m0 + i * 16;
      long long b = mm >> 11;
      long long s = mm & 2047;
      #pragma unroll
      for (int j = 0; j < 4; j++) {
        f16x4 pk;
        #pragma unroll
        for (int r = 0; r < 4; r++) pk[r] = (_Float16)acc[i][j][r];
        *(f16x4*)(Vt + (b << 21) + (long long)(d0 + j * 16) * 2048 + s) = pk;
      }
    }
  }
}

// ---------------- scores GEMM, 64x128 tiles, compact causal grid ----------------
// grid 1088 (1-D, XCD-swizzled): xcd = L&7 -> bz = xcd>>1, tile-half = xcd&1;
// t = (L>>3) + half*136 enumerates the 272 lower-tri tiles of that batch.
// 4 waves side-by-side in n (each 64m x 32n), swapped epilogue:
// acc[i][j][r] = S[m = 16i+l16][n = wn+16j+quad*4+r], i<4, j<2.
// Writes u = s - m_t fp16 into S[bz][2048][2048]; stats[bz][row][bx]={m_t,l_t}.
__global__ __launch_bounds__(256) void scores_gemm(
    const _Float16* __restrict__ Qh, const _Float16* __restrict__ Kh,
    _Float16* __restrict__ S, float2* __restrict__ stats) {
  int L = blockIdx.x;
  int xcd = L & 7;
  int bz = xcd >> 1;
  int t = (L >> 3) + (xcd & 1) * 136;
  int g = (int)((__builtin_sqrtf(4.0f * t + 1.0f) - 1.0f) * 0.5f);
  while ((g + 1) * (g + 2) <= t) g++;
  while (g * (g + 1) > t) g--;
  int rem = t - g * (g + 1);
  int by = 2 * g + (rem > g ? 1 : 0);         // 64-row tile index, 0..31
  int bxt = (rem > g) ? rem - (g + 1) : rem;  // 128-col tile index, 0..g
  bool diag = (bxt == g);

  const _Float16* Ab = Qh + (long long)bz * 2097152 + (long long)by * 64 * 1024;
  const _Float16* Bb = Kh + (long long)bz * 2097152 + (long long)bxt * 128 * 1024;

  __shared__ _Float16 lA[64 * 32];
  __shared__ _Float16 lB[128 * 32];
  __shared__ float redM[4][64];
  __shared__ float redL[4][64];

  int tid = threadIdx.x;
  int r0 = tid >> 2;
  int c0 = (tid & 3) * 8;
  const _Float16* ga0 = Ab + (long long)r0 * 1024 + c0;
  const _Float16* gb0 = Bb + (long long)r0 * 1024 + c0;
  const _Float16* gb1 = Bb + (long long)(r0 + 64) * 1024 + c0;
  _Float16* la0 = lA + tid * 8;
  _Float16* lb0 = lB + tid * 8;
  _Float16* lb1 = lB + 2048 + tid * 8;

  f32x4 acc[4][2] = {};
  int lane = tid & 63;
  int wv = tid >> 6;
  int wn = wv * 32;
  int l16 = lane & 15, quad = lane >> 4;
  const _Float16* raBase = lA + l16 * 32 + quad * 8;
  const _Float16* rbBase = lB + (wn + l16) * 32 + quad * 8;

  for (int kb = 0; kb < 1024; kb += 32) {
    __syncthreads();
    load16_lds(ga0, la0);
    load16_lds(gb0, lb0);
    load16_lds(gb1, lb1);
    ga0 += 32; gb0 += 32; gb1 += 32;
    __syncthreads();
    f16x8 af[4], bfr[2];
    #pragma unroll
    for (int i = 0; i < 4; i++) af[i] = *(const f16x8*)(raBase + i * 512);
    #pragma unroll
    for (int j = 0; j < 2; j++) bfr[j] = *(const f16x8*)(rbBase + j * 512);
    #pragma unroll
    for (int i = 0; i < 4; i++)
      #pragma unroll
      for (int j = 0; j < 2; j++)
        acc[i][j] = __builtin_amdgcn_mfma_f32_16x16x32_f16(bfr[j], af[i], acc[i][j], 0, 0, 0);
  }

  int rowBase = by * 64;
  int colBase = bxt * 128;

  // per-wave row max (masked on diagonal tile)
  float mloc[4];
  #pragma unroll
  for (int i = 0; i < 4; i++) {
    int grow = rowBase + 16 * i + l16;
    float mx = -3.0e38f;
    #pragma unroll
    for (int j = 0; j < 2; j++)
      #pragma unroll
      for (int r = 0; r < 4; r++) {
        bool ok = !diag || (colBase + wn + 16 * j + quad * 4 + r <= grow);
        mx = ok ? fmaxf(mx, acc[i][j][r]) : mx;
      }
    mx = fmaxf(mx, __shfl_xor(mx, 16));
    mx = fmaxf(mx, __shfl_xor(mx, 32));
    mloc[i] = mx;
  }
  if (quad == 0) {
    #pragma unroll
    for (int i = 0; i < 4; i++) redM[wv][16 * i + l16] = mloc[i];
  }
  __syncthreads();
  float mfin[4];
  #pragma unroll
  for (int i = 0; i < 4; i++) {
    int rl = 16 * i + l16;
    mfin[i] = fmaxf(fmaxf(redM[0][rl], redM[1][rl]), fmaxf(redM[2][rl], redM[3][rl]));
  }

  // per-wave sum of exp(s - m_t) (masked)
  float lloc[4];
  #pragma unroll
  for (int i = 0; i < 4; i++) {
    int grow = rowBase + 16 * i + l16;
    float sum = 0.f;
    #pragma unroll
    for (int j = 0; j < 2; j++)
      #pragma unroll
      for (int r = 0; r < 4; r++) {
        bool ok = !diag || (colBase + wn + 16 * j + quad * 4 + r <= grow);
        float e = __expf(acc[i][j][r] - mfin[i]);
        sum += ok ? e : 0.f;
      }
    sum += __shfl_xor(sum, 16);
    sum += __shfl_xor(sum, 32);
    lloc[i] = sum;
  }
  if (quad == 0) {
    #pragma unroll
    for (int i = 0; i < 4; i++) redL[wv][16 * i + l16] = lloc[i];
  }
  __syncthreads();
  if (wv == 0 && quad == 0) {
    #pragma unroll
    for (int i = 0; i < 4; i++) {
      int rl = 16 * i + l16;
      float lt = redL[0][rl] + redL[1][rl] + redL[2][rl] + redL[3][rl];
      stats[((long long)bz * 2048 + rowBase + rl) * 16 + bxt] =
          make_float2(mfin[i], lt);
    }
  }

  // store u = s - m_t as f16x4 (n-contiguous)
  _Float16* Sb = S + (long long)bz * 4194304;
  #pragma unroll
  for (int i = 0; i < 4; i++) {
    long long grow = rowBase + 16 * i + l16;
    #pragma unroll
    for (int j = 0; j < 2; j++) {
      f16x4 u;
      #pragma unroll
      for (int r = 0; r < 4; r++) u[r] = (_Float16)(acc[i][j][r] - mfin[i]);
      *(f16x4*)(Sb + grow * 2048 + (colBase + wn + 16 * j + quad * 4)) = u;
    }
  }
}

// ---------------- normalize: u -> p in place ----------------
__global__ __launch_bounds__(256) void normalize_p(_Float16* __restrict__ S,
                                                   const float2* __restrict__ stats) {
  int g = blockIdx.x;
  int bz = g >> 11, row = g & 2047;
  int nt = (row >> 7) + 1;
  _Float16* srow = S + ((long long)bz * 2048 + row) * 2048;
  const float2* st = stats + ((long long)bz * 2048 + row) * 16;
  __shared__ float sh_invl;
  __shared__ float shd[16];
  int t = threadIdx.x;
  if (t < 16) {
    float2 p = (t < nt) ? st[t] : make_float2(-3.0e38f, 0.f);
    float m = p.x;
    #pragma unroll
    for (int d = 1; d < 16; d <<= 1) m = fmaxf(m, __shfl_xor(m, d));
    float term = p.y * __expf(p.x - m);
    #pragma unroll
    for (int d = 1; d < 16; d <<= 1) term += __shfl_xor(term, d);
    shd[t] = p.x - m;
    if (t == 0) sh_invl = 1.0f / term;
  }
  __syncthreads();
  float invl = sh_invl;
  int Lp = nt << 7;
  for (int c = t; (c << 3) < Lp; c += 256) {
    float dt = shd[c >> 4];
    f16x8 v = ((f16x8*)srow)[c];
    f16x8 o;
    int col0 = c << 3;
    #pragma unroll
    for (int e = 0; e < 8; e++) {
      float u = (float)v[e];
      float pe = __expf(u + dt) * invl;
      o[e] = (col0 + e <= row) ? (_Float16)pe : (_Float16)0.f;
    }
    ((f16x8*)srow)[c] = o;
  }
}

// ---------------- split-K PV GEMM (XCD-swizzled 1-D grid) ----------------
// grid 768: xcd = bid&7 -> bz = xcd>>1, bx-half = xcd&1 (4 bx panels = 2 MB
// Vt slice, L2-resident). idx>>3: cy = idx>>2 (P panel reused by 4 adjacent
// bx blocks), bx = half*4 + (idx&3).
// cy<8: full row (k<=1024) -> Oh fp16 direct. cy>=8: fp32 partials P0/P1.
__global__ __launch_bounds__(256) void pv_splitk(
    const _Float16* __restrict__ P,   // S fp16 [bz][2048][2048]
    const _Float16* __restrict__ Vt,  // [b][1024][2048]
    float* __restrict__ P0, float* __restrict__ P1,
    _Float16* __restrict__ Oh) {
  int bid = blockIdx.x;
  int xcd = bid & 7;
  int bz = xcd >> 1;
  int idx = bid >> 3;             // 0..95
  int cy = idx >> 2;              // 0..23
  int bx = (xcd & 1) * 4 + (idx & 3);  // 0..7
  int by, c;
  if (cy < 8) { by = cy; c = 0; }
  else { int q = cy - 8; by = 8 + (q >> 1); c = q & 1; }
  int kmax = (by + 1) * 128;
  int k0 = c * 1024;
  int klen = min(kmax, k0 + 1024) - k0;

  const _Float16* Ab = P + (long long)bz * 4194304LL + (long long)by * 128 * 2048 + k0;
  const _Float16* Bb = Vt + (long long)bz * 2097152LL + (long long)bx * 128 * 2048 + k0;
  GEMM_PROLOGUE(Ab, 2048, Bb, 2048)
  GEMM_KLOOP(2048, 2048, klen, true)

  int m0 = by * 128 + wm + l16;
  int n0 = bx * 128 + wn + quad * 4;

  if (c == 0 && by < 8) {
    _Float16* C = Oh + (long long)bz * 2097152LL;
    #pragma unroll
    for (int i = 0; i < 4; i++)
      #pragma unroll
      for (int j = 0; j < 4; j++) {
        f16x4 pk;
        #pragma unroll
        for (int r = 0; r < 4; r++) pk[r] = (_Float16)acc[i][j][r];
        *(f16x4*)(C + (long long)(m0 + i * 16) * 1024 + (n0 + j * 16)) = pk;
      }
  } else if (c == 0) {
    float* C = P0 + (long long)bz * 2097152LL;
    #pragma unroll
    for (int i = 0; i < 4; i++)
      #pragma unroll
      for (int j = 0; j < 4; j++)
        *(f32x4*)(C + (long long)(m0 + i * 16) * 1024 + (n0 + j * 16)) = acc[i][j];
  } else {
    float* C = P1 + (long long)bz * 1048576LL;
    int mr = m0 - 1024;
    #pragma unroll
    for (int i = 0; i < 4; i++)
      #pragma unroll
      for (int j = 0; j < 4; j++)
        *(f32x4*)(C + (long long)(mr + i * 16) * 1024 + (n0 + j * 16)) = acc[i][j];
  }
}

// ---------------- PV reduce, upper 1024 rows only ----------------
__global__ __launch_bounds__(256) void pv_reduce(const float* __restrict__ P0,
                                                 const float* __restrict__ P1,
                                                 _Float16* __restrict__ Oh) {
  int i = blockIdx.x * 256 + threadIdx.x;
  if (i >= 1048576) return;
  int f4 = i;
  int bz = f4 >> 18;
  int loc = f4 & 262143;
  long long p0i = (long long)bz * 524288 + 262144 + loc;
  float4 v = ((const float4*)P0)[p0i];
  float4 w = ((const float4*)P1)[f4];
  v.x += w.x; v.y += w.y; v.z += w.z; v.w += w.w;
  f16x4 o;
  o[0] = (_Float16)v.x; o[1] = (_Float16)v.y; o[2] = (_Float16)v.z; o[3] = (_Float16)v.w;
  ((f16x4*)Oh)[p0i] = o;
}

// ---------------- output projection (+bias, fp32, swapped float4 stores) ----------------
__global__ __launch_bounds__(256) void oproj_gemm(
    const _Float16* __restrict__ A, const _Float16* __restrict__ B,
    float* __restrict__ C, const float* __restrict__ bias) {
  int bx = blockIdx.x, by = blockIdx.y;
  const _Float16* Ab = A + (long long)by * 128 * 1024;
  const _Float16* Bb = B + (long long)bx * 128 * 1024;
  GEMM_PROLOGUE(Ab, 1024, Bb, 1024)
  GEMM_KLOOP(1024, 1024, 1024, true)

  int m0 = by * 128 + wm + l16;
  int n0 = bx * 128 + wn + quad * 4;
  #pragma unroll
  for (int j = 0; j < 4; j++) {
    float4 b4 = *(const float4*)(bias + n0 + j * 16);
    #pragma unroll
    for (int i = 0; i < 4; i++) {
      f32x4 v = acc[i][j];
      v[0] += b4.x; v[1] += b4.y; v[2] += b4.z; v[3] += b4.w;
      *(f32x4*)(C + (long long)(m0 + i * 16) * 1024 + (n0 + j * 16)) = v;
    }
  }
}

// ---------------- workspace layout (bytes) ----------------
// xh   : 0          16,777,216   -> P1 alias during PV
// Wcat : 16777216    6,291,456
// Woh  : 23068672    2,097,152
// Qh   : 25165824   16,777,216   -> P0 alias (with Kh) during PV
// Kh   : 41943040   16,777,216
// Vt   : 58720256   16,777,216
// Oh   : 75497472   16,777,216
// Sb   : 92274688   33,554,432   fp16 u/p [4][2048][2048]
// stats: 125829120   1,048,576   float2 [4][2048][16]
// total: 126,877,696

extern "C" void kernel_launch(void* const* d_in, const int* in_sizes, int n_in,
                              void* d_out, int out_size, void* d_ws, size_t ws_size,
                              hipStream_t stream) {
  const float* x  = (const float*)d_in[0];
  const float* Wq = (const float*)d_in[1];
  const float* Wk = (const float*)d_in[2];
  const float* Wv = (const float*)d_in[3];
  const float* Wo = (const float*)d_in[4];
  const float* bO = (const float*)d_in[5];

  char* ws = (char*)d_ws;
  _Float16* xh   = (_Float16*)(ws + 0);
  _Float16* Wcat = (_Float16*)(ws + 16777216);
  _Float16* Woh  = (_Float16*)(ws + 23068672);
  _Float16* Qh   = (_Float16*)(ws + 25165824);
  _Float16* Kh   = (_Float16*)(ws + 41943040);
  _Float16* Vt   = (_Float16*)(ws + 58720256);
  _Float16* Oh   = (_Float16*)(ws + 75497472);
  _Float16* Sb   = (_Float16*)(ws + 92274688);
  float2*   stats= (float2*)  (ws + 125829120);
  float*    P0   = (float*)   (ws + 25165824);  // aliases Qh+Kh (dead by PV)
  float*    P1   = (float*)   (ws + 0);         // aliases xh (dead by PV)

  dim3 blk(256);

  cvt_all<<<12288, blk, 0, stream>>>(x, Wq, Wk, Wv, Wo, xh, Wcat, Woh);

  // fused Q/K/V projection (XCD-swizzled; B slice per XCD fits L2)
  qkv_gemm<<<1536, blk, 0, stream>>>(xh, Wcat, Qh, Kh, Vt);

  // scores + fused softmax statistics: 64x128 tiles, compact causal grid
  scores_gemm<<<1088, blk, 0, stream>>>(Qh, Kh, Sb, stats);

  // combine stats + normalize u -> p in place
  normalize_p<<<8192, blk, 0, stream>>>(Sb, stats);

  // O = P @ Vt^T with split-K (XCD-swizzled; Vt slice per XCD fits L2)
  pv_splitk<<<768, blk, 0, stream>>>(Sb, Vt, P0, P1, Oh);
  pv_reduce<<<4096, blk, 0, stream>>>(P0, P1, Oh);

  // out = O @ Wo^T + b_O
  oproj_gemm<<<dim3(8, 64, 1), blk, 0, stream>>>(Oh, Woh, (float*)d_out, bO);
}

// Round 8
// 278.705 us; speedup vs baseline: 1.1631x; 1.0701x over previous
//
#include <hip/hip_runtime.h>
#include <cstdint>

typedef _Float16 f16x8 __attribute__((ext_vector_type(8)));
typedef _Float16 f16x4 __attribute__((ext_vector_type(4)));
typedef float    f32x4 __attribute__((ext_vector_type(4)));

#define AS1 __attribute__((address_space(1)))
#define AS3 __attribute__((address_space(3)))

__device__ __forceinline__ void load16_lds(const void* g, void* l) {
  __builtin_amdgcn_global_load_lds((AS1 void*)g, (AS3 void*)l, 16, 0, 0);
}

// 128x128-tile K-loop, BK=64 via two BK=32 slabs (keeps the verified m97
// slab layout/bank behavior; halves barrier-drain count).
// SWAPPED variant: acc[i][j][r] = C[m = wm+16i+l16][n = wn+16j+quad*4+r]
// NORMAL  variant: acc[i][j][r] = C[m = wm+16i+quad*4+r][n = wn+16j+l16]
#define GEMM_PROLOGUE(Ab, lda, Bb, ldb)                                   \
  __shared__ _Float16 lA[2 * 128 * 32];                                   \
  __shared__ _Float16 lB[2 * 128 * 32];                                   \
  int tid = threadIdx.x;                                                  \
  int r0 = tid >> 2;                                                      \
  int c0 = (tid & 3) * 8;                                                 \
  const _Float16* ga0 = Ab + (long long)r0 * lda + c0;                    \
  const _Float16* ga1 = Ab + (long long)(r0 + 64) * lda + c0;             \
  const _Float16* gb0 = Bb + (long long)r0 * ldb + c0;                    \
  const _Float16* gb1 = Bb + (long long)(r0 + 64) * ldb + c0;             \
  _Float16* la0 = lA + tid * 8;                                           \
  _Float16* la1 = lA + 2048 + tid * 8;                                    \
  _Float16* la2 = lA + 4096 + tid * 8;                                    \
  _Float16* la3 = lA + 6144 + tid * 8;                                    \
  _Float16* lb0 = lB + tid * 8;                                           \
  _Float16* lb1 = lB + 2048 + tid * 8;                                    \
  _Float16* lb2 = lB + 4096 + tid * 8;                                    \
  _Float16* lb3 = lB + 6144 + tid * 8;                                    \
  f32x4 acc[4][4] = {};                                                   \
  int lane = tid & 63;                                                    \
  int wv = tid >> 6;                                                      \
  int wm = (wv & 1) * 64, wn = (wv >> 1) * 64;                            \
  int l16 = lane & 15, quad = lane >> 4;                                  \
  const _Float16* raBase = lA + (wm + l16) * 32 + quad * 8;               \
  const _Float16* rbBase = lB + (wn + l16) * 32 + quad * 8;

#define GEMM_KLOOP(lda, ldb, KLEN, SWAP)                                  \
  for (int kb = 0; kb < (KLEN); kb += 64) {                               \
    __syncthreads();                                                      \
    load16_lds(ga0, la0);                                                 \
    load16_lds(ga1, la1);                                                 \
    load16_lds(ga0 + 32, la2);                                            \
    load16_lds(ga1 + 32, la3);                                            \
    load16_lds(gb0, lb0);                                                 \
    load16_lds(gb1, lb1);                                                 \
    load16_lds(gb0 + 32, lb2);                                            \
    load16_lds(gb1 + 32, lb3);                                            \
    ga0 += 64; ga1 += 64; gb0 += 64; gb1 += 64;                           \
    __syncthreads();                                                      \
    _Pragma("unroll")                                                     \
    for (int s = 0; s < 2; s++) {                                         \
      f16x8 af[4], bfr[4];                                                \
      _Pragma("unroll")                                                   \
      for (int i = 0; i < 4; i++)                                         \
        af[i] = *(const f16x8*)(raBase + s * 4096 + i * 512);             \
      _Pragma("unroll")                                                   \
      for (int j = 0; j < 4; j++)                                         \
        bfr[j] = *(const f16x8*)(rbBase + s * 4096 + j * 512);            \
      _Pragma("unroll")                                                   \
      for (int i = 0; i < 4; i++)                                         \
        _Pragma("unroll")                                                 \
        for (int j = 0; j < 4; j++)                                       \
          acc[i][j] = (SWAP)                                              \
            ? __builtin_amdgcn_mfma_f32_16x16x32_f16(bfr[j], af[i], acc[i][j], 0, 0, 0) \
            : __builtin_amdgcn_mfma_f32_16x16x32_f16(af[i], bfr[j], acc[i][j], 0, 0, 0);\
    }                                                                     \
  }

// ---------------- fused fp32 -> fp16 convert for all 5 inputs ----------------
__global__ __launch_bounds__(256) void cvt_all(
    const float* __restrict__ x, const float* __restrict__ wq,
    const float* __restrict__ wk, const float* __restrict__ wv,
    const float* __restrict__ wo,
    _Float16* __restrict__ xh, _Float16* __restrict__ wcat,
    _Float16* __restrict__ woh) {
  long long g = (long long)blockIdx.x * 256 + threadIdx.x;
  const float* in; _Float16* out; long long idx;
  if (g < 2097152)      { in = x;  out = xh;             idx = g; }
  else if (g < 2359296) { in = wq; out = wcat;           idx = g - 2097152; }
  else if (g < 2621440) { in = wk; out = wcat + 1048576; idx = g - 2359296; }
  else if (g < 2883584) { in = wv; out = wcat + 2097152; idx = g - 2621440; }
  else                  { in = wo; out = woh;            idx = g - 2883584; }
  float4 v = ((const float4*)in)[idx];
  f16x4 o;
  o[0] = (_Float16)v.x; o[1] = (_Float16)v.y; o[2] = (_Float16)v.z; o[3] = (_Float16)v.w;
  ((f16x4*)out)[idx] = o;
}

// ---------------- fused QKV projection (XCD-swizzled 1-D grid) ----------------
__global__ __launch_bounds__(256) void qkv_gemm(
    const _Float16* __restrict__ A, const _Float16* __restrict__ B,
    _Float16* __restrict__ Qh, _Float16* __restrict__ Kh, _Float16* __restrict__ Vt) {
  int bid = blockIdx.x;
  int xcd = bid & 7;
  int idx = bid >> 3;       // 0..191
  int sub = idx % 3;
  int by  = idx / 3;        // 0..63
  int bx  = xcd * 3 + sub;  // 0..23

  const _Float16* Ab = A + (long long)by * 128 * 1024;
  const _Float16* Bb = B + (long long)bx * 128 * 1024;
  GEMM_PROLOGUE(Ab, 1024, Bb, 1024)

  if (bx < 16) {
    GEMM_KLOOP(1024, 1024, 1024, true)
    _Float16* C = (bx < 8) ? Qh : Kh;
    int m0 = by * 128 + wm + l16;
    int n0 = (bx & 7) * 128 + wn + quad * 4;
    #pragma unroll
    for (int i = 0; i < 4; i++)
      #pragma unroll
      for (int j = 0; j < 4; j++) {
        f16x4 pk;
        #pragma unroll
        for (int r = 0; r < 4; r++) pk[r] = (_Float16)acc[i][j][r];
        *(f16x4*)(C + (long long)(m0 + i * 16) * 1024 + (n0 + j * 16)) = pk;
      }
  } else {
    GEMM_KLOOP(1024, 1024, 1024, false)
    int m0 = by * 128 + wm + quad * 4;
    int d0 = (bx - 16) * 128 + wn + l16;
    #pragma unroll
    for (int i = 0; i < 4; i++) {
      long long mm = m0 + i * 16;
      long long b = mm >> 11;
      long long s = mm & 2047;
      #pragma unroll
      for (int j = 0; j < 4; j++) {
        f16x4 pk;
        #pragma unroll
        for (int r = 0; r < 4; r++) pk[r] = (_Float16)acc[i][j][r];
        *(f16x4*)(Vt + (b << 21) + (long long)(d0 + j * 16) * 2048 + s) = pk;
      }
    }
  }
}

// ---------------- scores GEMM, 64x128 tiles, compact causal grid, BK=64 ----------------
// grid 1088 (1-D, XCD-swizzled). 4 waves side-by-side in n (each 64m x 32n),
// swapped epilogue: acc[i][j][r] = S[m = 16i+l16][n = wn+16j+quad*4+r].
// Writes u = s - m_t fp16 into S[bz][2048][2048]; stats[bz][row][bx]={m_t,l_t}.
__global__ __launch_bounds__(256) void scores_gemm(
    const _Float16* __restrict__ Qh, const _Float16* __restrict__ Kh,
    _Float16* __restrict__ S, float2* __restrict__ stats) {
  int L = blockIdx.x;
  int xcd = L & 7;
  int bz = xcd >> 1;
  int t = (L >> 3) + (xcd & 1) * 136;
  int g = (int)((__builtin_sqrtf(4.0f * t + 1.0f) - 1.0f) * 0.5f);
  while ((g + 1) * (g + 2) <= t) g++;
  while (g * (g + 1) > t) g--;
  int rem = t - g * (g + 1);
  int by = 2 * g + (rem > g ? 1 : 0);         // 64-row tile index, 0..31
  int bxt = (rem > g) ? rem - (g + 1) : rem;  // 128-col tile index, 0..g
  bool diag = (bxt == g);

  const _Float16* Ab = Qh + (long long)bz * 2097152 + (long long)by * 64 * 1024;
  const _Float16* Bb = Kh + (long long)bz * 2097152 + (long long)bxt * 128 * 1024;

  __shared__ _Float16 lA[2 * 64 * 32];
  __shared__ _Float16 lB[2 * 128 * 32];
  __shared__ float redM[4][64];
  __shared__ float redL[4][64];

  int tid = threadIdx.x;
  int r0 = tid >> 2;
  int c0 = (tid & 3) * 8;
  const _Float16* ga0 = Ab + (long long)r0 * 1024 + c0;
  const _Float16* gb0 = Bb + (long long)r0 * 1024 + c0;
  const _Float16* gb1 = Bb + (long long)(r0 + 64) * 1024 + c0;
  _Float16* la0 = lA + tid * 8;
  _Float16* la1 = lA + 2048 + tid * 8;   // slab 1 (k 32..63)
  _Float16* lb0 = lB + tid * 8;
  _Float16* lb1 = lB + 2048 + tid * 8;
  _Float16* lb2 = lB + 4096 + tid * 8;   // slab 1
  _Float16* lb3 = lB + 6144 + tid * 8;

  f32x4 acc[4][2] = {};
  int lane = tid & 63;
  int wv = tid >> 6;
  int wn = wv * 32;
  int l16 = lane & 15, quad = lane >> 4;
  const _Float16* raBase = lA + l16 * 32 + quad * 8;
  const _Float16* rbBase = lB + (wn + l16) * 32 + quad * 8;

  for (int kb = 0; kb < 1024; kb += 64) {
    __syncthreads();
    load16_lds(ga0, la0);
    load16_lds(ga0 + 32, la1);
    load16_lds(gb0, lb0);
    load16_lds(gb1, lb1);
    load16_lds(gb0 + 32, lb2);
    load16_lds(gb1 + 32, lb3);
    ga0 += 64; gb0 += 64; gb1 += 64;
    __syncthreads();
    #pragma unroll
    for (int s = 0; s < 2; s++) {
      f16x8 af[4], bfr[2];
      #pragma unroll
      for (int i = 0; i < 4; i++) af[i] = *(const f16x8*)(raBase + s * 2048 + i * 512);
      #pragma unroll
      for (int j = 0; j < 2; j++) bfr[j] = *(const f16x8*)(rbBase + s * 4096 + j * 512);
      #pragma unroll
      for (int i = 0; i < 4; i++)
        #pragma unroll
        for (int j = 0; j < 2; j++)
          acc[i][j] = __builtin_amdgcn_mfma_f32_16x16x32_f16(bfr[j], af[i], acc[i][j], 0, 0, 0);
    }
  }

  int rowBase = by * 64;
  int colBase = bxt * 128;

  // per-wave row max (masked on diagonal tile)
  float mloc[4];
  #pragma unroll
  for (int i = 0; i < 4; i++) {
    int grow = rowBase + 16 * i + l16;
    float mx = -3.0e38f;
    #pragma unroll
    for (int j = 0; j < 2; j++)
      #pragma unroll
      for (int r = 0; r < 4; r++) {
        bool ok = !diag || (colBase + wn + 16 * j + quad * 4 + r <= grow);
        mx = ok ? fmaxf(mx, acc[i][j][r]) : mx;
      }
    mx = fmaxf(mx, __shfl_xor(mx, 16));
    mx = fmaxf(mx, __shfl_xor(mx, 32));
    mloc[i] = mx;
  }
  if (quad == 0) {
    #pragma unroll
    for (int i = 0; i < 4; i++) redM[wv][16 * i + l16] = mloc[i];
  }
  __syncthreads();
  float mfin[4];
  #pragma unroll
  for (int i = 0; i < 4; i++) {
    int rl = 16 * i + l16;
    mfin[i] = fmaxf(fmaxf(redM[0][rl], redM[1][rl]), fmaxf(redM[2][rl], redM[3][rl]));
  }

  // per-wave sum of exp(s - m_t) (masked)
  float lloc[4];
  #pragma unroll
  for (int i = 0; i < 4; i++) {
    int grow = rowBase + 16 * i + l16;
    float sum = 0.f;
    #pragma unroll
    for (int j = 0; j < 2; j++)
      #pragma unroll
      for (int r = 0; r < 4; r++) {
        bool ok = !diag || (colBase + wn + 16 * j + quad * 4 + r <= grow);
        float e = __expf(acc[i][j][r] - mfin[i]);
        sum += ok ? e : 0.f;
      }
    sum += __shfl_xor(sum, 16);
    sum += __shfl_xor(sum, 32);
    lloc[i] = sum;
  }
  if (quad == 0) {
    #pragma unroll
    for (int i = 0; i < 4; i++) redL[wv][16 * i + l16] = lloc[i];
  }
  __syncthreads();
  if (wv == 0 && quad == 0) {
    #pragma unroll
    for (int i = 0; i < 4; i++) {
      int rl = 16 * i + l16;
      float lt = redL[0][rl] + redL[1][rl] + redL[2][rl] + redL[3][rl];
      stats[((long long)bz * 2048 + rowBase + rl) * 16 + bxt] =
          make_float2(mfin[i], lt);
    }
  }

  // store u = s - m_t as f16x4 (n-contiguous)
  _Float16* Sb = S + (long long)bz * 4194304;
  #pragma unroll
  for (int i = 0; i < 4; i++) {
    long long grow = rowBase + 16 * i + l16;
    #pragma unroll
    for (int j = 0; j < 2; j++) {
      f16x4 u;
      #pragma unroll
      for (int r = 0; r < 4; r++) u[r] = (_Float16)(acc[i][j][r] - mfin[i]);
      *(f16x4*)(Sb + grow * 2048 + (colBase + wn + 16 * j + quad * 4)) = u;
    }
  }
}

// ---------------- normalize: u -> p in place ----------------
__global__ __launch_bounds__(256) void normalize_p(_Float16* __restrict__ S,
                                                   const float2* __restrict__ stats) {
  int g = blockIdx.x;
  int bz = g >> 11, row = g & 2047;
  int nt = (row >> 7) + 1;
  _Float16* srow = S + ((long long)bz * 2048 + row) * 2048;
  const float2* st = stats + ((long long)bz * 2048 + row) * 16;
  __shared__ float sh_invl;
  __shared__ float shd[16];
  int t = threadIdx.x;
  if (t < 16) {
    float2 p = (t < nt) ? st[t] : make_float2(-3.0e38f, 0.f);
    float m = p.x;
    #pragma unroll
    for (int d = 1; d < 16; d <<= 1) m = fmaxf(m, __shfl_xor(m, d));
    float term = p.y * __expf(p.x - m);
    #pragma unroll
    for (int d = 1; d < 16; d <<= 1) term += __shfl_xor(term, d);
    shd[t] = p.x - m;
    if (t == 0) sh_invl = 1.0f / term;
  }
  __syncthreads();
  float invl = sh_invl;
  int Lp = nt << 7;
  for (int c = t; (c << 3) < Lp; c += 256) {
    float dt = shd[c >> 4];
    f16x8 v = ((f16x8*)srow)[c];
    f16x8 o;
    int col0 = c << 3;
    #pragma unroll
    for (int e = 0; e < 8; e++) {
      float u = (float)v[e];
      float pe = __expf(u + dt) * invl;
      o[e] = (col0 + e <= row) ? (_Float16)pe : (_Float16)0.f;
    }
    ((f16x8*)srow)[c] = o;
  }
}

// ---------------- split-K PV GEMM (XCD-swizzled 1-D grid, BK=64) ----------------
__global__ __launch_bounds__(256) void pv_splitk(
    const _Float16* __restrict__ P,   // S fp16 [bz][2048][2048]
    const _Float16* __restrict__ Vt,  // [b][1024][2048]
    float* __restrict__ P0, float* __restrict__ P1,
    _Float16* __restrict__ Oh) {
  int bid = blockIdx.x;
  int xcd = bid & 7;
  int bz = xcd >> 1;
  int idx = bid >> 3;             // 0..95
  int cy = idx >> 2;              // 0..23
  int bx = (xcd & 1) * 4 + (idx & 3);  // 0..7
  int by, c;
  if (cy < 8) { by = cy; c = 0; }
  else { int q = cy - 8; by = 8 + (q >> 1); c = q & 1; }
  int kmax = (by + 1) * 128;
  int k0 = c * 1024;
  int klen = min(kmax, k0 + 1024) - k0;   // multiple of 128

  const _Float16* Ab = P + (long long)bz * 4194304LL + (long long)by * 128 * 2048 + k0;
  const _Float16* Bb = Vt + (long long)bz * 2097152LL + (long long)bx * 128 * 2048 + k0;
  GEMM_PROLOGUE(Ab, 2048, Bb, 2048)
  GEMM_KLOOP(2048, 2048, klen, true)

  int m0 = by * 128 + wm + l16;
  int n0 = bx * 128 + wn + quad * 4;

  if (c == 0 && by < 8) {
    _Float16* C = Oh + (long long)bz * 2097152LL;
    #pragma unroll
    for (int i = 0; i < 4; i++)
      #pragma unroll
      for (int j = 0; j < 4; j++) {
        f16x4 pk;
        #pragma unroll
        for (int r = 0; r < 4; r++) pk[r] = (_Float16)acc[i][j][r];
        *(f16x4*)(C + (long long)(m0 + i * 16) * 1024 + (n0 + j * 16)) = pk;
      }
  } else if (c == 0) {
    float* C = P0 + (long long)bz * 2097152LL;
    #pragma unroll
    for (int i = 0; i < 4; i++)
      #pragma unroll
      for (int j = 0; j < 4; j++)
        *(f32x4*)(C + (long long)(m0 + i * 16) * 1024 + (n0 + j * 16)) = acc[i][j];
  } else {
    float* C = P1 + (long long)bz * 1048576LL;
    int mr = m0 - 1024;
    #pragma unroll
    for (int i = 0; i < 4; i++)
      #pragma unroll
      for (int j = 0; j < 4; j++)
        *(f32x4*)(C + (long long)(mr + i * 16) * 1024 + (n0 + j * 16)) = acc[i][j];
  }
}

// ---------------- PV reduce, upper 1024 rows only ----------------
__global__ __launch_bounds__(256) void pv_reduce(const float* __restrict__ P0,
                                                 const float* __restrict__ P1,
                                                 _Float16* __restrict__ Oh) {
  int i = blockIdx.x * 256 + threadIdx.x;
  if (i >= 1048576) return;
  int f4 = i;
  int bz = f4 >> 18;
  int loc = f4 & 262143;
  long long p0i = (long long)bz * 524288 + 262144 + loc;
  float4 v = ((const float4*)P0)[p0i];
  float4 w = ((const float4*)P1)[f4];
  v.x += w.x; v.y += w.y; v.z += w.z; v.w += w.w;
  f16x4 o;
  o[0] = (_Float16)v.x; o[1] = (_Float16)v.y; o[2] = (_Float16)v.z; o[3] = (_Float16)v.w;
  ((f16x4*)Oh)[p0i] = o;
}

// ---------------- output projection (+bias, fp32, swapped float4 stores) ----------------
__global__ __launch_bounds__(256) void oproj_gemm(
    const _Float16* __restrict__ A, const _Float16* __restrict__ B,
    float* __restrict__ C, const float* __restrict__ bias) {
  int bx = blockIdx.x, by = blockIdx.y;
  const _Float16* Ab = A + (long long)by * 128 * 1024;
  const _Float16* Bb = B + (long long)bx * 128 * 1024;
  GEMM_PROLOGUE(Ab, 1024, Bb, 1024)
  GEMM_KLOOP(1024, 1024, 1024, true)

  int m0 = by * 128 + wm + l16;
  int n0 = bx * 128 + wn + quad * 4;
  #pragma unroll
  for (int j = 0; j < 4; j++) {
    float4 b4 = *(const float4*)(bias + n0 + j * 16);
    #pragma unroll
    for (int i = 0; i < 4; i++) {
      f32x4 v = acc[i][j];
      v[0] += b4.x; v[1] += b4.y; v[2] += b4.z; v[3] += b4.w;
      *(f32x4*)(C + (long long)(m0 + i * 16) * 1024 + (n0 + j * 16)) = v;
    }
  }
}

// ---------------- workspace layout (bytes) ----------------
// xh   : 0          16,777,216   -> P1 alias during PV
// Wcat : 16777216    6,291,456
// Woh  : 23068672    2,097,152
// Qh   : 25165824   16,777,216   -> P0 alias (with Kh) during PV
// Kh   : 41943040   16,777,216
// Vt   : 58720256   16,777,216
// Oh   : 75497472   16,777,216
// Sb   : 92274688   33,554,432   fp16 u/p [4][2048][2048]
// stats: 125829120   1,048,576   float2 [4][2048][16]
// total: 126,877,696

extern "C" void kernel_launch(void* const* d_in, const int* in_sizes, int n_in,
                              void* d_out, int out_size, void* d_ws, size_t ws_size,
                              hipStream_t stream) {
  const float* x  = (const float*)d_in[0];
  const float* Wq = (const float*)d_in[1];
  const float* Wk = (const float*)d_in[2];
  const float* Wv = (const float*)d_in[3];
  const float* Wo = (const float*)d_in[4];
  const float* bO = (const float*)d_in[5];

  char* ws = (char*)d_ws;
  _Float16* xh   = (_Float16*)(ws + 0);
  _Float16* Wcat = (_Float16*)(ws + 16777216);
  _Float16* Woh  = (_Float16*)(ws + 23068672);
  _Float16* Qh   = (_Float16*)(ws + 25165824);
  _Float16* Kh   = (_Float16*)(ws + 41943040);
  _Float16* Vt   = (_Float16*)(ws + 58720256);
  _Float16* Oh   = (_Float16*)(ws + 75497472);
  _Float16* Sb   = (_Float16*)(ws + 92274688);
  float2*   stats= (float2*)  (ws + 125829120);
  float*    P0   = (float*)   (ws + 25165824);  // aliases Qh+Kh (dead by PV)
  float*    P1   = (float*)   (ws + 0);         // aliases xh (dead by PV)

  dim3 blk(256);

  cvt_all<<<12288, blk, 0, stream>>>(x, Wq, Wk, Wv, Wo, xh, Wcat, Woh);

  // fused Q/K/V projection
  qkv_gemm<<<1536, blk, 0, stream>>>(xh, Wcat, Qh, Kh, Vt);

  // scores + fused softmax statistics: 64x128 tiles, compact causal grid
  scores_gemm<<<1088, blk, 0, stream>>>(Qh, Kh, Sb, stats);

  // combine stats + normalize u -> p in place
  normalize_p<<<8192, blk, 0, stream>>>(Sb, stats);

  // O = P @ Vt^T with split-K
  pv_splitk<<<768, blk, 0, stream>>>(Sb, Vt, P0, P1, Oh);
  pv_reduce<<<4096, blk, 0, stream>>>(P0, P1, Oh);

  // out = O @ Wo^T + b_O
  oproj_gemm<<<dim3(8, 64, 1), blk, 0, stream>>>(Oh, Woh, (float*)d_out, bO);
}